// Round 1
// baseline (86.840 us; speedup 1.0000x reference)
//
#include <hip/hip_runtime.h>

#define DIM 64
#define LANES_PER_EDGE 16

__global__ void __launch_bounds__(256) distmult_score_kernel(
        const float* __restrict__ X,      // [NUM_NODES, 64]
        const float* __restrict__ R,      // [NUM_REL, 64]
        const int*   __restrict__ src,    // [NUM_EDGES]
        const int*   __restrict__ tgt,    // [NUM_EDGES]
        const int*   __restrict__ rel,    // [NUM_EDGES]
        float*       __restrict__ out,    // [NUM_EDGES]
        int num_edges) {
    const int sub  = threadIdx.x & (LANES_PER_EDGE - 1);        // 0..15 within edge group
    const int epb  = blockDim.x / LANES_PER_EDGE;               // edges per block (16)
    int e          = blockIdx.x * epb + (threadIdx.x >> 4);
    const int estr = gridDim.x * epb;

    for (; e < num_edges; e += estr) {
        // All 16 lanes of a group load the same index -> HW broadcast.
        const int s = src[e];
        const int t = tgt[e];
        const int r = rel[e];

        // One float4 per lane: 16 lanes x 16 B = full 256 B row, coalesced.
        const float4 sv = *reinterpret_cast<const float4*>(X + (size_t)s * DIM + sub * 4);
        const float4 tv = *reinterpret_cast<const float4*>(X + (size_t)t * DIM + sub * 4);
        const float4 rv = *reinterpret_cast<const float4*>(R + (size_t)r * DIM + sub * 4);

        float acc = sv.x * rv.x * tv.x
                  + sv.y * rv.y * tv.y
                  + sv.z * rv.z * tv.z
                  + sv.w * rv.w * tv.w;

        // Reduce across the 16-lane edge group (wave64-safe: partners stay in-group).
        acc += __shfl_xor(acc, 1, 64);
        acc += __shfl_xor(acc, 2, 64);
        acc += __shfl_xor(acc, 4, 64);
        acc += __shfl_xor(acc, 8, 64);

        if (sub == 0) out[e] = acc;
    }
}

extern "C" void kernel_launch(void* const* d_in, const int* in_sizes, int n_in,
                              void* d_out, int out_size, void* d_ws, size_t ws_size,
                              hipStream_t stream) {
    const float* X         = (const float*)d_in[0];  // (100000, 64) f32
    const float* R         = (const float*)d_in[1];  // (237, 64) f32
    const int*   edge_list = (const int*)d_in[2];    // (2, NUM_EDGES) i32
    const int*   edge_type = (const int*)d_in[3];    // (1, NUM_EDGES) i32
    float*       out       = (float*)d_out;          // (NUM_EDGES,) f32

    const int num_edges = in_sizes[3];               // edge_type flat count = NUM_EDGES
    const int* src = edge_list;                      // row 0
    const int* tgt = edge_list + num_edges;          // row 1

    const int block = 256;
    const int epb   = block / LANES_PER_EDGE;        // 16 edges per block
    int grid = (num_edges + epb - 1) / epb;
    if (grid > 8192) grid = 8192;                    // grid-stride beyond this

    distmult_score_kernel<<<grid, block, 0, stream>>>(
        X, R, src, tgt, edge_type, out, num_edges);
}

// Round 2
// 81.123 us; speedup vs baseline: 1.0705x; 1.0705x over previous
//
#include <hip/hip_runtime.h>

#define DIM 64

__device__ __forceinline__ float dot3(const float4& a, const float4& b, const float4& c) {
    return a.x * b.x * c.x + a.y * b.y * c.y + a.z * b.z * c.z + a.w * b.w * c.w;
}

__global__ void __launch_bounds__(256) distmult_score_kernel(
        const float* __restrict__ X,      // [NUM_NODES, 64]
        const float* __restrict__ R,      // [NUM_REL, 64]
        const int*   __restrict__ src,    // [NUM_EDGES]
        const int*   __restrict__ tgt,    // [NUM_EDGES]
        const int*   __restrict__ rel,    // [NUM_EDGES]
        float*       __restrict__ out,    // [NUM_EDGES]
        int num_edges) {
    const int sub = threadIdx.x & 15;                 // lane within 16-lane edge group
    const int d0  = sub * 4;                          // feature offset for this lane
    int g = blockIdx.x * 16 + (threadIdx.x >> 4);     // group id; group g owns edges [4g, 4g+4)
    const int gstr = gridDim.x * 16;
    const int ngroups = (num_edges + 3) >> 2;

    for (; g < ngroups; g += gstr) {
        const int e0 = g << 2;
        if (e0 + 3 < num_edges) {
            // Broadcast index loads: all 16 lanes read the same int4 (HW broadcast);
            // the 4 groups of a wave read 64 contiguous bytes.
            const int4 s4 = *reinterpret_cast<const int4*>(src + e0);
            const int4 t4 = *reinterpret_cast<const int4*>(tgt + e0);
            const int4 r4 = *reinterpret_cast<const int4*>(rel + e0);

            // 12 independent float4 loads in flight per lane (4x MLP vs prev round).
            const float4 sv0 = *reinterpret_cast<const float4*>(X + (size_t)s4.x * DIM + d0);
            const float4 sv1 = *reinterpret_cast<const float4*>(X + (size_t)s4.y * DIM + d0);
            const float4 sv2 = *reinterpret_cast<const float4*>(X + (size_t)s4.z * DIM + d0);
            const float4 sv3 = *reinterpret_cast<const float4*>(X + (size_t)s4.w * DIM + d0);
            const float4 tv0 = *reinterpret_cast<const float4*>(X + (size_t)t4.x * DIM + d0);
            const float4 tv1 = *reinterpret_cast<const float4*>(X + (size_t)t4.y * DIM + d0);
            const float4 tv2 = *reinterpret_cast<const float4*>(X + (size_t)t4.z * DIM + d0);
            const float4 tv3 = *reinterpret_cast<const float4*>(X + (size_t)t4.w * DIM + d0);
            const float4 rv0 = *reinterpret_cast<const float4*>(R + (size_t)r4.x * DIM + d0);
            const float4 rv1 = *reinterpret_cast<const float4*>(R + (size_t)r4.y * DIM + d0);
            const float4 rv2 = *reinterpret_cast<const float4*>(R + (size_t)r4.z * DIM + d0);
            const float4 rv3 = *reinterpret_cast<const float4*>(R + (size_t)r4.w * DIM + d0);

            float a0 = dot3(sv0, rv0, tv0);
            float a1 = dot3(sv1, rv1, tv1);
            float a2 = dot3(sv2, rv2, tv2);
            float a3 = dot3(sv3, rv3, tv3);

            // 4 independent shuffle-reduce chains (ILP hides shfl latency).
            a0 += __shfl_xor(a0, 1, 64); a1 += __shfl_xor(a1, 1, 64);
            a2 += __shfl_xor(a2, 1, 64); a3 += __shfl_xor(a3, 1, 64);
            a0 += __shfl_xor(a0, 2, 64); a1 += __shfl_xor(a1, 2, 64);
            a2 += __shfl_xor(a2, 2, 64); a3 += __shfl_xor(a3, 2, 64);
            a0 += __shfl_xor(a0, 4, 64); a1 += __shfl_xor(a1, 4, 64);
            a2 += __shfl_xor(a2, 4, 64); a3 += __shfl_xor(a3, 4, 64);
            a0 += __shfl_xor(a0, 8, 64); a1 += __shfl_xor(a1, 8, 64);
            a2 += __shfl_xor(a2, 8, 64); a3 += __shfl_xor(a3, 8, 64);

            if (sub == 0)
                *reinterpret_cast<float4*>(out + e0) = make_float4(a0, a1, a2, a3);
        } else {
            // Tail (only if num_edges % 4 != 0)
            for (int e = e0; e < num_edges; ++e) {
                const int s = src[e], t = tgt[e], r = rel[e];
                const float4 sv = *reinterpret_cast<const float4*>(X + (size_t)s * DIM + d0);
                const float4 tv = *reinterpret_cast<const float4*>(X + (size_t)t * DIM + d0);
                const float4 rv = *reinterpret_cast<const float4*>(R + (size_t)r * DIM + d0);
                float acc = dot3(sv, rv, tv);
                acc += __shfl_xor(acc, 1, 64);
                acc += __shfl_xor(acc, 2, 64);
                acc += __shfl_xor(acc, 4, 64);
                acc += __shfl_xor(acc, 8, 64);
                if (sub == 0) out[e] = acc;
            }
        }
    }
}

extern "C" void kernel_launch(void* const* d_in, const int* in_sizes, int n_in,
                              void* d_out, int out_size, void* d_ws, size_t ws_size,
                              hipStream_t stream) {
    const float* X         = (const float*)d_in[0];  // (100000, 64) f32
    const float* R         = (const float*)d_in[1];  // (237, 64) f32
    const int*   edge_list = (const int*)d_in[2];    // (2, NUM_EDGES) i32
    const int*   edge_type = (const int*)d_in[3];    // (1, NUM_EDGES) i32
    float*       out       = (float*)d_out;          // (NUM_EDGES,) f32

    const int num_edges = in_sizes[3];
    const int* src = edge_list;
    const int* tgt = edge_list + num_edges;

    const int block = 256;
    const int ngroups = (num_edges + 3) >> 2;        // 4 edges per 16-lane group
    const int gpb = block / 16;                      // 16 groups per block
    int grid = (ngroups + gpb - 1) / gpb;            // exact grid: 1 iteration per group

    distmult_score_kernel<<<grid, block, 0, stream>>>(
        X, R, src, tgt, edge_type, out, num_edges);
}

// Round 3
// 51.921 us; speedup vs baseline: 1.6725x; 1.5624x over previous
//
#include <hip/hip_runtime.h>

#define DIM 64

// ---------- fp32 -> bf16 (RNE) packing ----------
__device__ __forceinline__ unsigned int bf16rne(float f) {
    unsigned int u = __float_as_uint(f);
    return (u + 0x7fffu + ((u >> 16) & 1u)) >> 16;
}
__device__ __forceinline__ unsigned int pack2(float lo, float hi) {
    return bf16rne(lo) | (bf16rne(hi) << 16);
}
// bf16 pair word -> two floats (pure bit ops, no cvt)
__device__ __forceinline__ float bl(unsigned int w) { return __uint_as_float(w << 16); }
__device__ __forceinline__ float bh(unsigned int w) { return __uint_as_float(w & 0xffff0000u); }

// Compress X (fp32, nwords*2 floats) into packed bf16 words. 8 floats/thread.
__global__ void __launch_bounds__(256) compress_X_kernel(
        const float* __restrict__ X, unsigned int* __restrict__ Xc, int nwords) {
    int w = (blockIdx.x * blockDim.x + threadIdx.x) * 4;
    if (w >= nwords) return;
    const float4 a = *reinterpret_cast<const float4*>(X + (size_t)w * 2);
    const float4 b = *reinterpret_cast<const float4*>(X + (size_t)w * 2 + 4);
    uint4 o;
    o.x = pack2(a.x, a.y);
    o.y = pack2(a.z, a.w);
    o.z = pack2(b.x, b.y);
    o.w = pack2(b.z, b.w);
    *reinterpret_cast<uint4*>(Xc + w) = o;
}

// dot over 8 features: s,t are 8 packed bf16 (uint4), r is 8 fp32 (2x float4)
__device__ __forceinline__ float edge_dot(const uint4& s, const uint4& t,
                                          const float4& ra, const float4& rb) {
    float acc = 0.f;
    acc = fmaf(bl(s.x) * bl(t.x), ra.x, acc);
    acc = fmaf(bh(s.x) * bh(t.x), ra.y, acc);
    acc = fmaf(bl(s.y) * bl(t.y), ra.z, acc);
    acc = fmaf(bh(s.y) * bh(t.y), ra.w, acc);
    acc = fmaf(bl(s.z) * bl(t.z), rb.x, acc);
    acc = fmaf(bh(s.z) * bh(t.z), rb.y, acc);
    acc = fmaf(bl(s.w) * bl(t.w), rb.z, acc);
    acc = fmaf(bh(s.w) * bh(t.w), rb.w, acc);
    return acc;
}

// 8 lanes per edge, 4 edges per group. X gathered as bf16 (1 cache line/row).
__global__ void __launch_bounds__(256) distmult_bf16_kernel(
        const unsigned int* __restrict__ Xc,  // [NUM_NODES, 32] packed words
        const float* __restrict__ R,          // [NUM_REL, 64] fp32
        const int*   __restrict__ src,
        const int*   __restrict__ tgt,
        const int*   __restrict__ rel,
        float*       __restrict__ out,
        int num_edges) {
    const int sub = threadIdx.x & 7;            // lane within 8-lane edge group
    const int w0  = sub * 4;                    // word offset in 32-word bf16 row
    const int f0  = sub * 8;                    // feature offset in fp32 R row
    int g = blockIdx.x * 32 + (threadIdx.x >> 3);
    const int gstr = gridDim.x * 32;
    const int ngroups = (num_edges + 3) >> 2;

    for (; g < ngroups; g += gstr) {
        const int e0 = g << 2;
        if (e0 + 3 < num_edges) {
            const int4 s4 = *reinterpret_cast<const int4*>(src + e0);
            const int4 t4 = *reinterpret_cast<const int4*>(tgt + e0);
            const int4 r4 = *reinterpret_cast<const int4*>(rel + e0);

            const uint4 sv0 = *reinterpret_cast<const uint4*>(Xc + (size_t)s4.x * 32 + w0);
            const uint4 sv1 = *reinterpret_cast<const uint4*>(Xc + (size_t)s4.y * 32 + w0);
            const uint4 sv2 = *reinterpret_cast<const uint4*>(Xc + (size_t)s4.z * 32 + w0);
            const uint4 sv3 = *reinterpret_cast<const uint4*>(Xc + (size_t)s4.w * 32 + w0);
            const uint4 tv0 = *reinterpret_cast<const uint4*>(Xc + (size_t)t4.x * 32 + w0);
            const uint4 tv1 = *reinterpret_cast<const uint4*>(Xc + (size_t)t4.y * 32 + w0);
            const uint4 tv2 = *reinterpret_cast<const uint4*>(Xc + (size_t)t4.z * 32 + w0);
            const uint4 tv3 = *reinterpret_cast<const uint4*>(Xc + (size_t)t4.w * 32 + w0);

            const float4 ra0 = *reinterpret_cast<const float4*>(R + (size_t)r4.x * DIM + f0);
            const float4 rb0 = *reinterpret_cast<const float4*>(R + (size_t)r4.x * DIM + f0 + 4);
            const float4 ra1 = *reinterpret_cast<const float4*>(R + (size_t)r4.y * DIM + f0);
            const float4 rb1 = *reinterpret_cast<const float4*>(R + (size_t)r4.y * DIM + f0 + 4);
            const float4 ra2 = *reinterpret_cast<const float4*>(R + (size_t)r4.z * DIM + f0);
            const float4 rb2 = *reinterpret_cast<const float4*>(R + (size_t)r4.z * DIM + f0 + 4);
            const float4 ra3 = *reinterpret_cast<const float4*>(R + (size_t)r4.w * DIM + f0);
            const float4 rb3 = *reinterpret_cast<const float4*>(R + (size_t)r4.w * DIM + f0 + 4);

            float a0 = edge_dot(sv0, tv0, ra0, rb0);
            float a1 = edge_dot(sv1, tv1, ra1, rb1);
            float a2 = edge_dot(sv2, tv2, ra2, rb2);
            float a3 = edge_dot(sv3, tv3, ra3, rb3);

            // reduce across the 8-lane group; 4 independent chains for ILP
            a0 += __shfl_xor(a0, 1, 64); a1 += __shfl_xor(a1, 1, 64);
            a2 += __shfl_xor(a2, 1, 64); a3 += __shfl_xor(a3, 1, 64);
            a0 += __shfl_xor(a0, 2, 64); a1 += __shfl_xor(a1, 2, 64);
            a2 += __shfl_xor(a2, 2, 64); a3 += __shfl_xor(a3, 2, 64);
            a0 += __shfl_xor(a0, 4, 64); a1 += __shfl_xor(a1, 4, 64);
            a2 += __shfl_xor(a2, 4, 64); a3 += __shfl_xor(a3, 4, 64);

            if (sub == 0)
                *reinterpret_cast<float4*>(out + e0) = make_float4(a0, a1, a2, a3);
        } else {
            for (int e = e0; e < num_edges; ++e) {
                const int s = src[e], t = tgt[e], r = rel[e];
                const uint4  sv = *reinterpret_cast<const uint4*>(Xc + (size_t)s * 32 + w0);
                const uint4  tv = *reinterpret_cast<const uint4*>(Xc + (size_t)t * 32 + w0);
                const float4 ra = *reinterpret_cast<const float4*>(R + (size_t)r * DIM + f0);
                const float4 rb = *reinterpret_cast<const float4*>(R + (size_t)r * DIM + f0 + 4);
                float acc = edge_dot(sv, tv, ra, rb);
                acc += __shfl_xor(acc, 1, 64);
                acc += __shfl_xor(acc, 2, 64);
                acc += __shfl_xor(acc, 4, 64);
                if (sub == 0) out[e] = acc;
            }
        }
    }
}

// ---------- fp32 fallback (only if ws too small; same as round-1 scheme) ----------
__global__ void __launch_bounds__(256) distmult_f32_kernel(
        const float* __restrict__ X, const float* __restrict__ R,
        const int* __restrict__ src, const int* __restrict__ tgt,
        const int* __restrict__ rel, float* __restrict__ out, int num_edges) {
    const int sub = threadIdx.x & 15;
    int e = blockIdx.x * 16 + (threadIdx.x >> 4);
    const int estr = gridDim.x * 16;
    for (; e < num_edges; e += estr) {
        const int s = src[e], t = tgt[e], r = rel[e];
        const float4 sv = *reinterpret_cast<const float4*>(X + (size_t)s * DIM + sub * 4);
        const float4 tv = *reinterpret_cast<const float4*>(X + (size_t)t * DIM + sub * 4);
        const float4 rv = *reinterpret_cast<const float4*>(R + (size_t)r * DIM + sub * 4);
        float acc = sv.x * rv.x * tv.x + sv.y * rv.y * tv.y
                  + sv.z * rv.z * tv.z + sv.w * rv.w * tv.w;
        acc += __shfl_xor(acc, 1, 64);
        acc += __shfl_xor(acc, 2, 64);
        acc += __shfl_xor(acc, 4, 64);
        acc += __shfl_xor(acc, 8, 64);
        if (sub == 0) out[e] = acc;
    }
}

extern "C" void kernel_launch(void* const* d_in, const int* in_sizes, int n_in,
                              void* d_out, int out_size, void* d_ws, size_t ws_size,
                              hipStream_t stream) {
    const float* X         = (const float*)d_in[0];  // (100000, 64) f32
    const float* R         = (const float*)d_in[1];  // (237, 64) f32
    const int*   edge_list = (const int*)d_in[2];    // (2, NUM_EDGES) i32
    const int*   edge_type = (const int*)d_in[3];    // (1, NUM_EDGES) i32
    float*       out       = (float*)d_out;

    const int num_edges = in_sizes[3];
    const int nx        = in_sizes[0];               // X element count (6.4M)
    const int* src = edge_list;
    const int* tgt = edge_list + num_edges;

    const size_t need = (size_t)nx * 2;              // bf16 copy of X
    if (ws_size >= need && (nx % 8) == 0) {
        unsigned int* Xc = (unsigned int*)d_ws;
        const int nwords = nx / 2;

        const int cthreads = nwords / 4;             // 8 floats per thread
        compress_X_kernel<<<(cthreads + 255) / 256, 256, 0, stream>>>(X, Xc, nwords);

        const int ngroups = (num_edges + 3) >> 2;    // 4 edges per 8-lane group
        const int gpb = 256 / 8;                     // 32 groups per block
        int grid = (ngroups + gpb - 1) / gpb;
        distmult_bf16_kernel<<<grid, 256, 0, stream>>>(
            Xc, R, src, tgt, edge_type, out, num_edges);
    } else {
        int grid = (num_edges + 15) / 16;
        if (grid > 8192) grid = 8192;
        distmult_f32_kernel<<<grid, 256, 0, stream>>>(
            X, R, src, tgt, edge_type, out, num_edges);
    }
}